// Round 4
// baseline (785.239 us; speedup 1.0000x reference)
//
#include <hip/hip_runtime.h>

#define B 64
#define T 2000
#define D_MEM 512
#define D_Q 1024
#define D_ATT 128
#define C_LOC 32
#define K 31

// energy tiling: 20 chunks of 100 t's per batch -> grid(20,64)
#define CH2 100
#define NCH2 (T / CH2)          // 20
// ctx streaming: 40 chunks of 50 t's -> grid(40,64)
#define CH3 50
#define NPART (T / CH3)         // 40
#define AWW 132                 // s_aw row width: 130 used, padded for 16B align

// ws layout (floats)
#define WS_PQ    0
#define WS_EXPW  (WS_PQ + B * D_ATT)     // unnormalized exp(e)  [B,T]
#define WS_SUMS  (WS_EXPW + B * T)       // per-chunk sums       [B,NCH2]
#define WS_PART  (WS_SUMS + B * NCH2)    // ctx partials         [NPART,B,D_MEM]

__device__ __forceinline__ float tanh_fast(float x) {
    float e = __expf(2.f * x);
    return 1.f - 2.f / (e + 1.f);
}

// K1: pq[b,d] = sum_i h[b,i]*Wq[i,d]. grid(B), block(512): 4 i-slices x 128 d.
__global__ __launch_bounds__(512) void pq_kernel(const float* __restrict__ h,
                                                 const float* __restrict__ Wq,
                                                 float* __restrict__ pq) {
    int b = blockIdx.x;
    int tid = threadIdx.x;
    int ty = tid >> 7;          // 0..3  (i-slice)
    int d  = tid & 127;         // 0..127
    __shared__ float sh[D_Q];
    __shared__ float red[4][D_ATT];
    const float* hb = h + (size_t)b * D_Q;
    if (tid < D_Q / 4) ((float4*)sh)[tid] = ((const float4*)hb)[tid];
    __syncthreads();
    float acc = 0.f;
    int ibeg = ty * 256;
#pragma unroll 8
    for (int i2 = 0; i2 < 256; ++i2) {
        int i = ibeg + i2;
        acc = fmaf(sh[i], Wq[(size_t)i * D_ATT + d], acc);
    }
    red[ty][d] = acc;
    __syncthreads();
    if (ty == 0)
        pq[b * D_ATT + d] = red[0][d] + red[1][d] + red[2][d] + red[3][d];
}

// Energy finish for one row: e = v . tanh(pq + pl + pm), 32-lane reduce, exp.
#define EFIN(PL, PM, ROW)                                                    \
    {                                                                        \
        float e = vv.x * tanh_fast(pqv.x + (PL).x + (PM).x)                  \
                + vv.y * tanh_fast(pqv.y + (PL).y + (PM).y)                  \
                + vv.z * tanh_fast(pqv.z + (PL).z + (PM).z)                  \
                + vv.w * tanh_fast(pqv.w + (PL).w + (PM).w);                 \
        e += __shfl_xor(e, 16); e += __shfl_xor(e, 8);                       \
        e += __shfl_xor(e, 4);  e += __shfl_xor(e, 2);                       \
        e += __shfl_xor(e, 1);                                               \
        if (dd == 0) s_e[ROW] = __expf(e);                                   \
    }

// proj inner: 4 c's (one loc quad L against wloc quads w0..w3) into PL.
// c-order ascending (4cq+0..3) -> bit-identical to the scalar-c version.
#define PROJ4(PL, L)                                                          \
    (PL).x = fmaf((L).x, w0.x, (PL).x); (PL).y = fmaf((L).x, w0.y, (PL).y);   \
    (PL).z = fmaf((L).x, w0.z, (PL).z); (PL).w = fmaf((L).x, w0.w, (PL).w);   \
    (PL).x = fmaf((L).y, w1.x, (PL).x); (PL).y = fmaf((L).y, w1.y, (PL).y);   \
    (PL).z = fmaf((L).y, w1.z, (PL).z); (PL).w = fmaf((L).y, w1.w, (PL).w);   \
    (PL).x = fmaf((L).z, w2.x, (PL).x); (PL).y = fmaf((L).z, w2.y, (PL).y);   \
    (PL).z = fmaf((L).z, w2.z, (PL).z); (PL).w = fmaf((L).z, w2.w, (PL).w);   \
    (PL).x = fmaf((L).w, w3.x, (PL).x); (PL).y = fmaf((L).w, w3.y, (PL).y);   \
    (PL).z = fmaf((L).w, w3.z, (PL).z); (PL).w = fmaf((L).w, w3.w, (PL).w);

// K2: conv -> loc-proj -> energy -> exp -> chunk sum.
// R3 post-mortem: kernel was LDS-instruction-bound (~9000 LDS-pipe cyc/wave:
// conv 868 scalar b32 reads + proj 128 b32 + 32 b128 per jc ~= 75 us/CU).
// Fix: vectorize ALL LDS access. Conv: 4 CONSECUTIVE rows per thread,
// sliding-window float4 of s_aw (broadcast) + transposed-padded wc quads.
// Proj: s_loc read as broadcast quads (4 c's at once). Per-row k-order and
// c-order unchanged -> bit-identical numerics.
__global__ __launch_bounds__(256, 4) void energy_kernel(
    const float* __restrict__ aw, const float* __restrict__ pmem,
    const float* __restrict__ pq, const float* __restrict__ Wconv,
    const float* __restrict__ bconv, const float* __restrict__ Wloc,
    const float* __restrict__ v, float* __restrict__ expw,
    float* __restrict__ sums) {
    const int s = blockIdx.x, b = blockIdx.y;
    const int t0 = s * CH2;
    const int tid = threadIdx.x;

    __shared__ float s_aw[2][AWW];           // 1056 B (rows 16B-aligned)
    __shared__ float s_wc2[C_LOC * 68];      // 8704 B: [c][i*32+k], pads zeroed
    __shared__ float s_loc[CH2][C_LOC];      // 12800 B
    __shared__ float s_wloc[C_LOC * D_ATT];  // 16384 B
    __shared__ float s_pq[D_ATT];            // 512 B
    __shared__ float s_e[CH2];               // 400 B
    __shared__ float s_red[2];               // total ~39.9 KB -> 4 blocks/CU

    for (int j = tid; j < 2 * AWW; j += 256) {
        int i = j / AWW, o = j - i * AWW;
        int t = t0 - (K / 2) + o;
        s_aw[i][o] = (o < 130 && t >= 0 && t < T)
                         ? aw[((size_t)b * 2 + i) * T + t] : 0.f;
    }
    // transposed conv weights: s_wc2[c*68 + i*32 + k]
    for (int j = tid; j < C_LOC * 2 * K; j += 256) {
        int c = j / (2 * K), r = j - c * 2 * K;
        int i = r / K, k = r - i * K;
        s_wc2[c * 68 + i * 32 + k] = Wconv[j];
    }
    if (tid < C_LOC) {                       // zero the quad pads (k=31 slots)
        s_wc2[tid * 68 + 31] = 0.f;
        s_wc2[tid * 68 + 63] = 0.f;
    }
    for (int j = tid; j < C_LOC * D_ATT / 4; j += 256)
        ((float4*)s_wloc)[j] = ((const float4*)Wloc)[j];
    if (tid < D_ATT) s_pq[tid] = pq[b * D_ATT + tid];
    __syncthreads();

    // ---- conv: thread (g=tid>>5, c=tid&31) handles row-quads q = g+8p ----
    // rows 4q..4q+3; sliding float4 window over s_aw (broadcast reads).
    {
        int g = tid >> 5, c = tid & 31;
        float bc = bconv[c];
        const float4* wc4 = (const float4*)&s_wc2[c * 68];   // 272B stride, 16B ok
#pragma unroll
        for (int p = 0; p < 4; ++p) {
            int q = g + 8 * p;               // quad index; valid q <= 24
            if (q <= 24) {                   // uniform per 32-lane group
                int r = 4 * q;
                float a0 = bc, a1 = bc, a2 = bc, a3 = bc;
#pragma unroll
                for (int i = 0; i < 2; ++i) {
                    const float4* aw4 = (const float4*)&s_aw[i][0];
                    float4 A = aw4[q];
#pragma unroll
                    for (int kq = 0; kq < 8; ++kq) {
                        float4 Bq = aw4[q + kq + 1];
                        float4 wv = wc4[i * 8 + kq];
                        // k = 4kq+0: rows need aw[r+4kq + rr]
                        a0 = fmaf(A.x, wv.x, a0);
                        a1 = fmaf(A.y, wv.x, a1);
                        a2 = fmaf(A.z, wv.x, a2);
                        a3 = fmaf(A.w, wv.x, a3);
                        // k = 4kq+1
                        a0 = fmaf(A.y, wv.y, a0);
                        a1 = fmaf(A.z, wv.y, a1);
                        a2 = fmaf(A.w, wv.y, a2);
                        a3 = fmaf(Bq.x, wv.y, a3);
                        // k = 4kq+2
                        a0 = fmaf(A.z, wv.z, a0);
                        a1 = fmaf(A.w, wv.z, a1);
                        a2 = fmaf(Bq.x, wv.z, a2);
                        a3 = fmaf(Bq.y, wv.z, a3);
                        if (kq < 7) {        // k = 4kq+3 (k=31 doesn't exist)
                            a0 = fmaf(A.w, wv.w, a0);
                            a1 = fmaf(Bq.x, wv.w, a1);
                            a2 = fmaf(Bq.y, wv.w, a2);
                            a3 = fmaf(Bq.z, wv.w, a3);
                        }
                        A = Bq;
                    }
                }
                s_loc[r + 0][c] = a0;
                s_loc[r + 1][c] = a1;
                s_loc[r + 2][c] = a2;
                s_loc[r + 3][c] = a3;
            }
        }
    }
    __syncthreads();

    // ---- energy + exp: 3 groups of 4 rows, quad LDS reads, then tail ----
    {
        int g = tid >> 5, dd = tid & 31;
        float4 pqv = ((const float4*)s_pq)[dd];
        float4 vv  = ((const float4*)v)[dd];
        const float4* pmb =
            (const float4*)(pmem + ((size_t)b * T + t0) * D_ATT);
        const float4* wl4 = (const float4*)s_wloc;     // [c][dquad]
        const float4* lc4 = (const float4*)&s_loc[0][0]; // row stride 8 quads

        for (int jc = 0; jc < 3; ++jc) {
            int r0 = g + 32 * jc;            // rows r0, r0+8, r0+16, r0+24 <= 95
            float4 pm0 = pmb[(size_t)(r0)      * (D_ATT / 4) + dd];
            float4 pm1 = pmb[(size_t)(r0 +  8) * (D_ATT / 4) + dd];
            float4 pm2 = pmb[(size_t)(r0 + 16) * (D_ATT / 4) + dd];
            float4 pm3 = pmb[(size_t)(r0 + 24) * (D_ATT / 4) + dd];
            float4 pl0 = make_float4(0.f, 0.f, 0.f, 0.f);
            float4 pl1 = make_float4(0.f, 0.f, 0.f, 0.f);
            float4 pl2 = make_float4(0.f, 0.f, 0.f, 0.f);
            float4 pl3 = make_float4(0.f, 0.f, 0.f, 0.f);
#pragma unroll
            for (int cq = 0; cq < 8; ++cq) {
                float4 w0 = wl4[(4 * cq + 0) * (D_ATT / 4) + dd];
                float4 w1 = wl4[(4 * cq + 1) * (D_ATT / 4) + dd];
                float4 w2 = wl4[(4 * cq + 2) * (D_ATT / 4) + dd];
                float4 w3 = wl4[(4 * cq + 3) * (D_ATT / 4) + dd];
                float4 l0 = lc4[(size_t)(r0)      * (C_LOC / 4) + cq];
                float4 l1 = lc4[(size_t)(r0 +  8) * (C_LOC / 4) + cq];
                float4 l2 = lc4[(size_t)(r0 + 16) * (C_LOC / 4) + cq];
                float4 l3 = lc4[(size_t)(r0 + 24) * (C_LOC / 4) + cq];
                PROJ4(pl0, l0);
                PROJ4(pl1, l1);
                PROJ4(pl2, l2);
                PROJ4(pl3, l3);
            }
            EFIN(pl0, pm0, r0);
            EFIN(pl1, pm1, r0 + 8);
            EFIN(pl2, pm2, r0 + 16);
            EFIN(pl3, pm3, r0 + 24);
        }

        // tail: row g+96, valid iff g<4 (uniform across the 32 dd-lanes)
        {
            int tl = g + 96;
            if (tl < CH2) {
                float4 pm = pmb[(size_t)tl * (D_ATT / 4) + dd];
                float4 pl = make_float4(0.f, 0.f, 0.f, 0.f);
#pragma unroll
                for (int cq = 0; cq < 8; ++cq) {
                    float4 w0 = wl4[(4 * cq + 0) * (D_ATT / 4) + dd];
                    float4 w1 = wl4[(4 * cq + 1) * (D_ATT / 4) + dd];
                    float4 w2 = wl4[(4 * cq + 2) * (D_ATT / 4) + dd];
                    float4 w3 = wl4[(4 * cq + 3) * (D_ATT / 4) + dd];
                    float4 l0 = lc4[(size_t)tl * (C_LOC / 4) + cq];
                    PROJ4(pl, l0);
                }
                EFIN(pl, pm, tl);
            }
        }
    }
    __syncthreads();

    // ---- chunk sum + stash unnormalized weights ----
    if (tid < 128) {
        float vsum = (tid < CH2) ? s_e[tid] : 0.f;
        if (tid < CH2) expw[(size_t)b * T + t0 + tid] = vsum;
        float r = vsum;
#pragma unroll
        for (int off = 32; off >= 1; off >>= 1) r += __shfl_xor(r, off);
        if ((tid & 63) == 0) s_red[tid >> 6] = r;
    }
    __syncthreads();
    if (tid == 0) sums[b * NCH2 + s] = s_red[0] + s_red[1];
}

// K3: pure `memory` streamer. grid(NPART=40, B), block(128).
// launch_bounds(128,8) -> up to 16 blocks/CU; grid 2560 = 10/CU -> fully
// resident in one dispatch wave. Partial accumulation grouping identical to
// the original fused kernel -> bit-identical numerics. Also emits out_w.
__global__ __launch_bounds__(128, 8) void ctx_kernel(
    const float* __restrict__ expw, const float* __restrict__ sums,
    const float* __restrict__ memory, float* __restrict__ partial,
    float* __restrict__ out_w) {
    const int p = blockIdx.x, b = blockIdx.y;
    const int t0 = p * CH3;
    const int tid = threadIdx.x;
    __shared__ float s_w[CH3];
    __shared__ float s_inv;
    if (tid < 64) {
        float r = (tid < NCH2) ? sums[b * NCH2 + tid] : 0.f;
#pragma unroll
        for (int off = 32; off >= 1; off >>= 1) r += __shfl_xor(r, off);
        if (tid == 0) s_inv = 1.f / r;
    }
    if (tid < CH3) s_w[tid] = expw[(size_t)b * T + t0 + tid];
    __syncthreads();
    if (tid < CH3) out_w[(size_t)b * T + t0 + tid] = s_w[tid] * s_inv;

    const float4* mem4 = (const float4*)(memory + ((size_t)b * T + t0) * D_MEM);
    float4 acc = {0.f, 0.f, 0.f, 0.f};
#pragma unroll 10
    for (int j = 0; j < CH3; ++j) {
        float wt = s_w[j];
        float4 mv = mem4[(size_t)j * (D_MEM / 4) + tid];
        acc.x = fmaf(wt, mv.x, acc.x);
        acc.y = fmaf(wt, mv.y, acc.y);
        acc.z = fmaf(wt, mv.z, acc.z);
        acc.w = fmaf(wt, mv.w, acc.w);
    }
    ((float4*)(partial + ((size_t)p * B + b) * D_MEM))[tid] = acc;
}

// K4: reduce the 40 unnormalized partials, scale by inv (same order as the
// original finalize: partial sum first, then *inv -> identical numerics).
__global__ __launch_bounds__(128) void finalize_kernel(
    const float* __restrict__ sums, const float* __restrict__ partial,
    float* __restrict__ out_ctx) {
    int b = blockIdx.x, tid = threadIdx.x;
    __shared__ float s_inv;
    if (tid < 64) {
        float r = (tid < NCH2) ? sums[b * NCH2 + tid] : 0.f;
#pragma unroll
        for (int off = 32; off >= 1; off >>= 1) r += __shfl_xor(r, off);
        if (tid == 0) s_inv = 1.f / r;
    }
    __syncthreads();
    float inv = s_inv;
    const float4* p4 = (const float4*)partial;
    float4 acc = {0.f, 0.f, 0.f, 0.f};
#pragma unroll
    for (int p = 0; p < NPART; ++p) {
        float4 pv = p4[((size_t)p * B + b) * (D_MEM / 4) + tid];
        acc.x += pv.x; acc.y += pv.y; acc.z += pv.z; acc.w += pv.w;
    }
    acc.x *= inv; acc.y *= inv; acc.z *= inv; acc.w *= inv;
    ((float4*)(out_ctx + (size_t)b * D_MEM))[tid] = acc;
}

extern "C" void kernel_launch(void* const* d_in, const int* in_sizes, int n_in,
                              void* d_out, int out_size, void* d_ws, size_t ws_size,
                              hipStream_t stream) {
    const float* hidden = (const float*)d_in[0];   // [B,1,D_Q]
    const float* memory = (const float*)d_in[1];   // [B,T,D_MEM]
    const float* pmem   = (const float*)d_in[2];   // [B,T,D_ATT]
    const float* aw     = (const float*)d_in[3];   // [B,2,T]
    const float* Wq     = (const float*)d_in[4];   // [D_Q,D_ATT]
    const float* Wconv  = (const float*)d_in[5];   // [C_LOC,2,K]
    const float* bconv  = (const float*)d_in[6];   // [C_LOC]
    const float* Wloc   = (const float*)d_in[7];   // [C_LOC,D_ATT]
    const float* v      = (const float*)d_in[8];   // [D_ATT]

    float* out_ctx = (float*)d_out;                // [B,D_MEM]
    float* out_w   = (float*)d_out + B * D_MEM;    // [B,T]

    float* ws      = (float*)d_ws;
    float* pqp     = ws + WS_PQ;
    float* expw    = ws + WS_EXPW;
    float* sums    = ws + WS_SUMS;
    float* partial = ws + WS_PART;

    pq_kernel<<<B, 512, 0, stream>>>(hidden, Wq, pqp);
    energy_kernel<<<dim3(NCH2, B), 256, 0, stream>>>(aw, pmem, pqp, Wconv,
                                                     bconv, Wloc, v, expw, sums);
    ctx_kernel<<<dim3(NPART, B), 128, 0, stream>>>(expw, sums, memory, partial,
                                                   out_w);
    finalize_kernel<<<B, 128, 0, stream>>>(sums, partial, out_ctx);
}